// Round 11
// baseline (624.996 us; speedup 1.0000x reference)
//
#include <hip/hip_runtime.h>
#include <stdint.h>

#define M_DIM 4096   // BATCH*SEQ
#define N_DIM 16384  // OUT_FEATURES
#define K_DIM 4096   // IN_FEATURES
#define BM 256
#define BN 256
#define BK 64
#define NT (K_DIM / BK)   // 64 K-tiles

typedef __attribute__((ext_vector_type(8))) __bf16 bf16x8;
typedef __attribute__((ext_vector_type(4))) float f32x4;

// fp32 -> bf16 bits, round-to-nearest-even
__device__ __forceinline__ unsigned short f2bf(float f) {
    uint32_t u = __builtin_bit_cast(uint32_t, f);
    uint32_t r = (u + 0x7FFFu + ((u >> 16) & 1u)) >> 16;
    return (unsigned short)r;
}

union Pack8 { unsigned short h[8]; uint4 v; };

__device__ __forceinline__ void async_copy16(const void* g, void* l) {
    __builtin_amdgcn_global_load_lds((__attribute__((address_space(1))) void*)(g),
                                     (__attribute__((address_space(3))) void*)(l),
                                     16, 0, 0);
}

#define BARRIER() do { asm volatile("" ::: "memory"); \
                       __builtin_amdgcn_s_barrier();  \
                       asm volatile("" ::: "memory"); } while (0)

// ---------------- phase 0: cast x fp32 -> bf16 ----------------
__global__ __launch_bounds__(256) void cast_x_kernel(const float* __restrict__ x,
                                                     unsigned short* __restrict__ xb,
                                                     int n8) {
    for (int i = blockIdx.x * blockDim.x + threadIdx.x; i < n8;
         i += gridDim.x * blockDim.x) {
        const float4* p = (const float4*)(x + (size_t)i * 8);
        float4 v0 = p[0], v1 = p[1];
        Pack8 o;
        o.h[0] = f2bf(v0.x); o.h[1] = f2bf(v0.y);
        o.h[2] = f2bf(v0.z); o.h[3] = f2bf(v0.w);
        o.h[4] = f2bf(v1.x); o.h[5] = f2bf(v1.y);
        o.h[6] = f2bf(v1.z); o.h[7] = f2bf(v1.w);
        *(uint4*)(xb + (size_t)i * 8) = o.v;
    }
}

// ---------------- phase 1: dequant weights -> bf16 ----------------
__global__ __launch_bounds__(256) void dequant_kernel(const int* __restrict__ stored,
                                                      const int* __restrict__ sign,
                                                      const float* __restrict__ log_min,
                                                      const float* __restrict__ log_max,
                                                      unsigned short* __restrict__ wb,
                                                      int n8) {
    const float lmin = log_min[0];
    const float lrange = log_max[0] - lmin;
    for (int i = blockIdx.x * blockDim.x + threadIdx.x; i < n8;
         i += gridDim.x * blockDim.x) {
        const int4* ps = (const int4*)(stored + (size_t)i * 8);
        const int4* pg = (const int4*)(sign + (size_t)i * 8);
        int4 s0 = ps[0], s1 = ps[1];
        int4 g0 = pg[0], g1 = pg[1];
        int sv[8] = {s0.x, s0.y, s0.z, s0.w, s1.x, s1.y, s1.z, s1.w};
        int gv[8] = {g0.x, g0.y, g0.z, g0.w, g1.x, g1.y, g1.z, g1.w};
        Pack8 o;
#pragma unroll
        for (int j = 0; j < 8; ++j) {
            float nrm = (255.0f - (float)sv[j]) * (1.0f / 254.0f);
            float w = __expf(lmin + nrm * lrange);
            o.h[j] = f2bf(gv[j] ? w : -w);
        }
        *(uint4*)(wb + (size_t)i * 8) = o.v;
    }
}

// ---------------- phase 2: 256x256 bf16 GEMM — cross-phase read prefetch, counted lgkm ----------------
// A: [M][K] bf16, W: [N][K] bf16, C: [M][N] fp32
// LDS 160 KiB: A bufs p=t%3 at p*32768 (halves +0/+16384; 128 rows x 128 B each);
// B bufs c=t&1 at 98304 + c*32768 (halves +0/+16384).
// Swizzle involution: byte ^= ((row&7)<<4); global_load_lds dest linear, global
// SOURCE pre-inverse-swizzled, same XOR on ds_read addresses (rule #21).
//
// Port-overlap schedule: reads for phase q+1 are issued AFTER phase q's first
// barrier and BEFORE phase q's MFMA; the compiler emits a COUNTED lgkmcnt before
// the MFMA (waits only the operands it needs), so the prefetched reads execute
// on the LDS port UNDER the MFMA cluster.
// Per tile t, phase q in {0,1,2,3} (= C-quadrant (q>>1, q&1)):
//   q0: stage B(t+1).h0;                BAR; read bF1;        SB; MFMA aF0xbF0; BAR
//   q1: stage B(t+1).h1;                BAR; read aF1;        SB; MFMA aF0xbF1; BAR
//   q2: stage A(t+2).h0;                BAR; (no reads)       SB; MFMA aF1xbF0; BAR
//   q3: stage A(t+2).h1; vmcnt(4|0);    BAR; read aF0,bF0 of t+1 (next bufs);
//                                                             SB; MFMA aF1xbF1; BAR
// vmcnt ledger at q3 (steady, 12 outstanding: A(t+1) 4, B(t+1) 4, A(t+2) 4):
// vmcnt(4) drains A(t+1)+B(t+1) -> next-tile reads (issued AFTER the barrier,
// so all waves' stages are drained) are safe; A(t+2) stays in flight.
// Tail: t >= NT-2 uses vmcnt(0). Cross-wave hazards audited: every stage targets
// a buffer whose last readers are >=3 barriers behind (A bufs: overwrite A(t-1),
// last read q1 of t-1; B bufs: overwrite B(t-1), last read q0 of t-1).
__global__ __launch_bounds__(512, 2) void gemm_kernel(const unsigned short* __restrict__ A,
                                                      const unsigned short* __restrict__ W,
                                                      const float* __restrict__ bias,
                                                      float* __restrict__ C) {
    extern __shared__ char lds[];
    const int tid  = threadIdx.x;
    const int wave = tid >> 6;
    const int lane = tid & 63;
    const int l15  = lane & 15;
    const int l16  = lane >> 4;
    const int wr   = wave >> 2;   // 0..1 -> 128-row band (A half)
    const int wc   = wave & 3;    // 0..3 -> 64-col band (B half wc>>1, rows (wc&1)*64)

    // T1: XCD swizzle. nwg=1024 (%8==0); each XCD: 2 M-rows x all N -> A panel L2-hot.
    const int bid = blockIdx.x;
    const int wg  = ((bid & 7) << 7) | (bid >> 3);
    const int rowBase = (wg >> 6) * BM;
    const int colBase = (wg & 63) * BN;

    f32x4 acc[8][4] = {};

    auto stage_half_A = [&](int t, int h) {   // 2 gloads
        const int kb = t * BK;
        char* hb = lds + (t % 3) * 32768 + h * 16384;
        const int rb = rowBase + h * 128;
#pragma unroll
        for (int sub = 0; sub < 2; ++sub) {
            const int Ld   = (sub * 512 + tid) * 16;
            const int r    = Ld >> 7;
            const int colb = (Ld & 127) ^ ((r & 7) << 4);     // inverse-swz source
            async_copy16(A + (size_t)(rb + r) * K_DIM + kb + (colb >> 1),
                         hb + (sub * 512 + wave * 64) * 16);  // wave-uniform dest
        }
    };
    auto stage_half_B = [&](int t, int h) {   // 2 gloads
        const int kb = t * BK;
        char* hb = lds + 98304 + (t & 1) * 32768 + h * 16384;
        const int rb = colBase + h * 128;
#pragma unroll
        for (int sub = 0; sub < 2; ++sub) {
            const int Ld   = (sub * 512 + tid) * 16;
            const int r    = Ld >> 7;
            const int colb = (Ld & 127) ^ ((r & 7) << 4);
            async_copy16(W + (size_t)(rb + r) * K_DIM + kb + (colb >> 1),
                         hb + (sub * 512 + wave * 64) * 16);
        }
    };

    // prologue: A(0)->buf0, A(1)->buf1, B(0)->bufB0 (12 loads); drain; read q0 frags
    stage_half_A(0, 0); stage_half_A(0, 1);
    stage_half_A(1, 0); stage_half_A(1, 1);
    stage_half_B(0, 0); stage_half_B(0, 1);
    asm volatile("s_waitcnt vmcnt(0)" ::: "memory");
    BARRIER();

    const int brB = (wc & 1) * 64;
    bf16x8 aF0[4][2], aF1[4][2], bF0[2][2], bF1[2][2];
    {
        const char* bA = lds + wr * 16384;
        const char* bB = lds + 98304 + (wc >> 1) * 16384;
#pragma unroll
        for (int i = 0; i < 4; ++i)
#pragma unroll
            for (int ks = 0; ks < 2; ++ks) {
                const int r    = i * 16 + l15;
                const int colb = (ks * 64 + l16 * 16) ^ ((r & 7) << 4);
                aF0[i][ks] = *(const bf16x8*)(bA + (r << 7) + colb);
            }
#pragma unroll
        for (int j = 0; j < 2; ++j)
#pragma unroll
            for (int ks = 0; ks < 2; ++ks) {
                const int r    = brB + j * 16 + l15;
                const int colb = (ks * 64 + l16 * 16) ^ ((r & 7) << 4);
                bF0[j][ks] = *(const bf16x8*)(bB + (r << 7) + colb);
            }
    }

    for (int t = 0; t < NT; ++t) {
        const char* bA = lds + (t % 3) * 32768 + wr * 16384;
        const char* bB = lds + 98304 + (t & 1) * 32768 + (wc >> 1) * 16384;

        // ================= q0: MFMA aF0 x bF0 ; prefetch bF1 =================
        if (t + 1 < NT) stage_half_B(t + 1, 0);
        BARRIER();
#pragma unroll
        for (int j = 0; j < 2; ++j)
#pragma unroll
            for (int ks = 0; ks < 2; ++ks) {
                const int r    = brB + 32 + j * 16 + l15;
                const int colb = (ks * 64 + l16 * 16) ^ ((r & 7) << 4);
                bF1[j][ks] = *(const bf16x8*)(bB + (r << 7) + colb);
            }
        __builtin_amdgcn_sched_barrier(0);
        __builtin_amdgcn_s_setprio(1);
#pragma unroll
        for (int i = 0; i < 4; ++i)
#pragma unroll
            for (int j = 0; j < 2; ++j)
#pragma unroll
                for (int ks = 0; ks < 2; ++ks)
                    acc[i][j] = __builtin_amdgcn_mfma_f32_16x16x32_bf16(
                        aF0[i][ks], bF0[j][ks], acc[i][j], 0, 0, 0);
        __builtin_amdgcn_s_setprio(0);
        BARRIER();

        // ================= q1: MFMA aF0 x bF1 ; prefetch aF1 =================
        if (t + 1 < NT) stage_half_B(t + 1, 1);
        BARRIER();
#pragma unroll
        for (int i = 0; i < 4; ++i)
#pragma unroll
            for (int ks = 0; ks < 2; ++ks) {
                const int r    = 64 + i * 16 + l15;
                const int colb = (ks * 64 + l16 * 16) ^ ((r & 7) << 4);
                aF1[i][ks] = *(const bf16x8*)(bA + (r << 7) + colb);
            }
        __builtin_amdgcn_sched_barrier(0);
        __builtin_amdgcn_s_setprio(1);
#pragma unroll
        for (int i = 0; i < 4; ++i)
#pragma unroll
            for (int j = 0; j < 2; ++j)
#pragma unroll
                for (int ks = 0; ks < 2; ++ks)
                    acc[i][2 + j] = __builtin_amdgcn_mfma_f32_16x16x32_bf16(
                        aF0[i][ks], bF1[j][ks], acc[i][2 + j], 0, 0, 0);
        __builtin_amdgcn_s_setprio(0);
        BARRIER();

        // ================= q2: MFMA aF1 x bF0 =================
        if (t + 2 < NT) stage_half_A(t + 2, 0);
        BARRIER();
        __builtin_amdgcn_sched_barrier(0);
        __builtin_amdgcn_s_setprio(1);
#pragma unroll
        for (int i = 0; i < 4; ++i)
#pragma unroll
            for (int j = 0; j < 2; ++j)
#pragma unroll
                for (int ks = 0; ks < 2; ++ks)
                    acc[4 + i][j] = __builtin_amdgcn_mfma_f32_16x16x32_bf16(
                        aF1[i][ks], bF0[j][ks], acc[4 + i][j], 0, 0, 0);
        __builtin_amdgcn_s_setprio(0);
        BARRIER();

        // ================= q3: MFMA aF1 x bF1 ; prefetch next-tile aF0,bF0 =================
        if (t + 2 < NT) stage_half_A(t + 2, 1);
        if (t < NT - 2) asm volatile("s_waitcnt vmcnt(4)" ::: "memory");
        else            asm volatile("s_waitcnt vmcnt(0)" ::: "memory");
        BARRIER();
        if (t + 1 < NT) {
            const char* nA = lds + ((t + 1) % 3) * 32768 + wr * 16384;
            const char* nB = lds + 98304 + ((t + 1) & 1) * 32768 + (wc >> 1) * 16384;
#pragma unroll
            for (int i = 0; i < 4; ++i)
#pragma unroll
                for (int ks = 0; ks < 2; ++ks) {
                    const int r    = i * 16 + l15;
                    const int colb = (ks * 64 + l16 * 16) ^ ((r & 7) << 4);
                    aF0[i][ks] = *(const bf16x8*)(nA + (r << 7) + colb);
                }
#pragma unroll
            for (int j = 0; j < 2; ++j)
#pragma unroll
                for (int ks = 0; ks < 2; ++ks) {
                    const int r    = brB + j * 16 + l15;
                    const int colb = (ks * 64 + l16 * 16) ^ ((r & 7) << 4);
                    bF0[j][ks] = *(const bf16x8*)(nB + (r << 7) + colb);
                }
        }
        __builtin_amdgcn_sched_barrier(0);
        __builtin_amdgcn_s_setprio(1);
#pragma unroll
        for (int i = 0; i < 4; ++i)
#pragma unroll
            for (int j = 0; j < 2; ++j)
#pragma unroll
                for (int ks = 0; ks < 2; ++ks)
                    acc[4 + i][2 + j] = __builtin_amdgcn_mfma_f32_16x16x32_bf16(
                        aF1[i][ks], bF1[j][ks], acc[4 + i][2 + j], 0, 0, 0);
        __builtin_amdgcn_s_setprio(0);
        BARRIER();
    }

    // epilogue: C/D layout col=lane&15, row=(lane>>4)*4+reg (m89/m91-verified)
#pragma unroll
    for (int m = 0; m < 8; ++m) {
        const int grow0 = rowBase + wr * 128 + m * 16 + l16 * 4;
#pragma unroll
        for (int n = 0; n < 4; ++n) {
            const int gcol = colBase + wc * 64 + n * 16 + l15;
            const float bv = bias[gcol];
#pragma unroll
            for (int r4 = 0; r4 < 4; ++r4)
                C[(size_t)(grow0 + r4) * N_DIM + gcol] = acc[m][n][r4] + bv;
        }
    }
}

extern "C" void kernel_launch(void* const* d_in, const int* in_sizes, int n_in,
                              void* d_out, int out_size, void* d_ws, size_t ws_size,
                              hipStream_t stream) {
    const float* x       = (const float*)d_in[0];
    const int*   stored  = (const int*)d_in[1];
    const int*   sign    = (const int*)d_in[2];
    const float* log_min = (const float*)d_in[3];
    const float* log_max = (const float*)d_in[4];
    const float* bias    = (const float*)d_in[5];
    float* out = (float*)d_out;

    unsigned short* Ab = (unsigned short*)d_ws;                         // 32 MB
    unsigned short* Wb = (unsigned short*)((char*)d_ws +
                          (size_t)M_DIM * K_DIM * sizeof(unsigned short)); // +128 MB

    cast_x_kernel<<<2048, 256, 0, stream>>>(x, Ab, (M_DIM * K_DIM) / 8);
    dequant_kernel<<<4096, 256, 0, stream>>>(stored, sign, log_min, log_max, Wb,
                                             (N_DIM * K_DIM) / 8);

    hipFuncSetAttribute((const void*)gemm_kernel,
                        hipFuncAttributeMaxDynamicSharedMemorySize, 163840);
    gemm_kernel<<<dim3((M_DIM / BM) * (N_DIM / BN)), dim3(512), 163840, stream>>>(
        Ab, Wb, bias, out);
}

// Round 12
// 617.891 us; speedup vs baseline: 1.0115x; 1.0115x over previous
//
#include <hip/hip_runtime.h>
#include <stdint.h>

#define M_DIM 4096   // BATCH*SEQ
#define N_DIM 16384  // OUT_FEATURES
#define K_DIM 4096   // IN_FEATURES
#define BM 256
#define BN 256
#define BK 64
#define NT (K_DIM / BK)   // 64 K-tiles

typedef __attribute__((ext_vector_type(8))) __bf16 bf16x8;
typedef __attribute__((ext_vector_type(4))) float f32x4;

// fp32 -> bf16 bits, round-to-nearest-even
__device__ __forceinline__ unsigned short f2bf(float f) {
    uint32_t u = __builtin_bit_cast(uint32_t, f);
    uint32_t r = (u + 0x7FFFu + ((u >> 16) & 1u)) >> 16;
    return (unsigned short)r;
}

union Pack8 { unsigned short h[8]; uint4 v; };

__device__ __forceinline__ void async_copy16(const void* g, void* l) {
    __builtin_amdgcn_global_load_lds((__attribute__((address_space(1))) void*)(g),
                                     (__attribute__((address_space(3))) void*)(l),
                                     16, 0, 0);
}

#define BARRIER() do { asm volatile("" ::: "memory"); \
                       __builtin_amdgcn_s_barrier();  \
                       asm volatile("" ::: "memory"); } while (0)

// ---------------- phase 0: cast x fp32 -> bf16 ----------------
__global__ __launch_bounds__(256) void cast_x_kernel(const float* __restrict__ x,
                                                     unsigned short* __restrict__ xb,
                                                     int n8) {
    for (int i = blockIdx.x * blockDim.x + threadIdx.x; i < n8;
         i += gridDim.x * blockDim.x) {
        const float4* p = (const float4*)(x + (size_t)i * 8);
        float4 v0 = p[0], v1 = p[1];
        Pack8 o;
        o.h[0] = f2bf(v0.x); o.h[1] = f2bf(v0.y);
        o.h[2] = f2bf(v0.z); o.h[3] = f2bf(v0.w);
        o.h[4] = f2bf(v1.x); o.h[5] = f2bf(v1.y);
        o.h[6] = f2bf(v1.z); o.h[7] = f2bf(v1.w);
        *(uint4*)(xb + (size_t)i * 8) = o.v;
    }
}

// ---------------- phase 1: dequant weights -> bf16 ----------------
__global__ __launch_bounds__(256) void dequant_kernel(const int* __restrict__ stored,
                                                      const int* __restrict__ sign,
                                                      const float* __restrict__ log_min,
                                                      const float* __restrict__ log_max,
                                                      unsigned short* __restrict__ wb,
                                                      int n8) {
    const float lmin = log_min[0];
    const float lrange = log_max[0] - lmin;
    for (int i = blockIdx.x * blockDim.x + threadIdx.x; i < n8;
         i += gridDim.x * blockDim.x) {
        const int4* ps = (const int4*)(stored + (size_t)i * 8);
        const int4* pg = (const int4*)(sign + (size_t)i * 8);
        int4 s0 = ps[0], s1 = ps[1];
        int4 g0 = pg[0], g1 = pg[1];
        int sv[8] = {s0.x, s0.y, s0.z, s0.w, s1.x, s1.y, s1.z, s1.w};
        int gv[8] = {g0.x, g0.y, g0.z, g0.w, g1.x, g1.y, g1.z, g1.w};
        Pack8 o;
#pragma unroll
        for (int j = 0; j < 8; ++j) {
            float nrm = (255.0f - (float)sv[j]) * (1.0f / 254.0f);
            float w = __expf(lmin + nrm * lrange);
            o.h[j] = f2bf(gv[j] ? w : -w);
        }
        *(uint4*)(wb + (size_t)i * 8) = o.v;
    }
}

// ---------------- phase 2: 256x256 bf16 GEMM, 2-barrier/K-tile, reg-pipelined ----------------
// R5 configuration — empirical best (480 us GEMM, MfmaUtil 52.4%, 0 conflicts).
// A: [M][K] bf16, W: [N][K] bf16, C: [M][N] fp32
// LDS (128 KiB): dbuf c: A half h at c*65536 + h*16384 (128 rows x 128 B, swizzled);
// B half h at c*65536 + 32768 + h*16384. Swizzle involution: byte ^= ((row&7)<<4);
// global_load_lds dest linear, global SOURCE pre-inverse-swizzled (rule #21).
//
// Per K-tile t (c = t&1), quadrants q=(mq,nq) of the per-wave 128x64 C-tile:
//   top:  vmcnt(4) [A(t),B(t) landed; A(t+1) still in flight]; BARRIER
//   q0:   read aF0(8) + bF0(4) + prefetch bF1(4); stage B.h0(t+1)->c^1; MFMA aF0xbF0
//   q1:   prefetch aF1(8); stage B.h1(t+1)->c^1;                        MFMA aF0xbF1
//   q2:   (read-free)                                                   MFMA aF1xbF0
//   BARRIER  [all waves' A-c reads complete -> A slots of c reusable]
//   q3:   stage A.h0+h1(t+2)->c;                                        MFMA aF1xbF1
// Cross-wave hazards: B(t+1)->c^1 safe via tile-top barrier (t-1's B reads done);
// A(t+2)->c safe via end-q2 barrier. All fragment waits: per-wave dataflow (compiler
// emits counted lgkmcnt). vmcnt ledger at top of t: [B(t) 4, A(t+1) 4] -> vmcnt(4).
__global__ __launch_bounds__(512, 2) void gemm_kernel(const unsigned short* __restrict__ A,
                                                      const unsigned short* __restrict__ W,
                                                      const float* __restrict__ bias,
                                                      float* __restrict__ C) {
    extern __shared__ char lds[];
    const int tid  = threadIdx.x;
    const int wave = tid >> 6;
    const int lane = tid & 63;
    const int l15  = lane & 15;
    const int l16  = lane >> 4;
    const int wr   = wave >> 2;   // 0..1 -> 128-row band (A half wr)
    const int wc   = wave & 3;    // 0..3 -> 64-col band (B half wc>>1, rows (wc&1)*64)

    // T1: XCD swizzle. nwg=1024 (%8==0); each XCD: 2 M-rows x all N -> A panel L2-hot.
    const int bid = blockIdx.x;
    const int wg  = ((bid & 7) << 7) | (bid >> 3);
    const int rowBase = (wg >> 6) * BM;
    const int colBase = (wg & 63) * BN;

    f32x4 acc[8][4] = {};

    // stage one half-tile u (0=A.h0,1=A.h1,2=B.h0,3=B.h1) of tile t into dbuf d
    auto stage_half = [&](int t, int d, int u) {
        const int kb = t * BK;
        const unsigned short* g = (u < 2) ? A : W;
        const int rb = ((u < 2) ? rowBase : colBase) + (u & 1) * 128;
        char* hb = lds + d * 65536 + ((u < 2) ? 0 : 32768) + (u & 1) * 16384;
#pragma unroll
        for (int sub = 0; sub < 2; ++sub) {
            const int Ld   = (sub * 512 + tid) * 16;              // linear dest byte
            const int r    = Ld >> 7;                             // row (128 B/row)
            const int colb = (Ld & 127) ^ ((r & 7) << 4);         // inverse-swz source
            async_copy16(g + (size_t)(rb + r) * K_DIM + kb + (colb >> 1),
                         hb + (sub * 512 + wave * 64) * 16);      // wave-uniform dest
        }
    };

    // prologue: tile 0 (all 4 halves) + tile 1's A halves
    stage_half(0, 0, 0); stage_half(0, 0, 1);
    stage_half(0, 0, 2); stage_half(0, 0, 3);
    stage_half(1, 1, 0); stage_half(1, 1, 1);

    for (int t = 0; t < NT; ++t) {
        const int c = t & 1;
        if (t + 1 < NT) asm volatile("s_waitcnt vmcnt(4)" ::: "memory");
        else            asm volatile("s_waitcnt vmcnt(0)" ::: "memory");
        BARRIER();

        const char* bA  = lds + c * 65536 + wr * 16384;
        const char* bB  = lds + c * 65536 + 32768 + (wc >> 1) * 16384;
        const int   brB = (wc & 1) * 64;

        bf16x8 aF0[4][2], aF1[4][2], bF0[2][2], bF1[2][2];

        // ---- q0: reads + B-prefetch + stage, then MFMA quadrant (0,0) ----
#pragma unroll
        for (int i = 0; i < 4; ++i)
#pragma unroll
            for (int ks = 0; ks < 2; ++ks) {
                const int r    = i * 16 + l15;                     // mq=0 rows 0..63
                const int colb = (ks * 64 + l16 * 16) ^ ((r & 7) << 4);
                aF0[i][ks] = *(const bf16x8*)(bA + (r << 7) + colb);
            }
#pragma unroll
        for (int j = 0; j < 2; ++j)
#pragma unroll
            for (int ks = 0; ks < 2; ++ks) {
                const int r    = brB + j * 16 + l15;               // nq=0 rows
                const int colb = (ks * 64 + l16 * 16) ^ ((r & 7) << 4);
                bF0[j][ks] = *(const bf16x8*)(bB + (r << 7) + colb);
            }
#pragma unroll
        for (int j = 0; j < 2; ++j)
#pragma unroll
            for (int ks = 0; ks < 2; ++ks) {
                const int r    = brB + 32 + j * 16 + l15;          // nq=1 rows (prefetch)
                const int colb = (ks * 64 + l16 * 16) ^ ((r & 7) << 4);
                bF1[j][ks] = *(const bf16x8*)(bB + (r << 7) + colb);
            }
        if (t + 1 < NT) stage_half(t + 1, c ^ 1, 2);               // B.h0(t+1)
        __builtin_amdgcn_s_setprio(1);
#pragma unroll
        for (int i = 0; i < 4; ++i)
#pragma unroll
            for (int j = 0; j < 2; ++j)
#pragma unroll
                for (int ks = 0; ks < 2; ++ks)
                    acc[i][j] = __builtin_amdgcn_mfma_f32_16x16x32_bf16(
                        aF0[i][ks], bF0[j][ks], acc[i][j], 0, 0, 0);
        __builtin_amdgcn_s_setprio(0);

        // ---- q1: A-prefetch + stage, MFMA quadrant (0,1) ----
#pragma unroll
        for (int i = 0; i < 4; ++i)
#pragma unroll
            for (int ks = 0; ks < 2; ++ks) {
                const int r    = 64 + i * 16 + l15;                // mq=1 rows 64..127
                const int colb = (ks * 64 + l16 * 16) ^ ((r & 7) << 4);
                aF1[i][ks] = *(const bf16x8*)(bA + (r << 7) + colb);
            }
        if (t + 1 < NT) stage_half(t + 1, c ^ 1, 3);               // B.h1(t+1)
        __builtin_amdgcn_s_setprio(1);
#pragma unroll
        for (int i = 0; i < 4; ++i)
#pragma unroll
            for (int j = 0; j < 2; ++j)
#pragma unroll
                for (int ks = 0; ks < 2; ++ks)
                    acc[i][2 + j] = __builtin_amdgcn_mfma_f32_16x16x32_bf16(
                        aF0[i][ks], bF1[j][ks], acc[i][2 + j], 0, 0, 0);
        __builtin_amdgcn_s_setprio(0);

        // ---- q2: read-free, MFMA quadrant (1,0) ----
        __builtin_amdgcn_s_setprio(1);
#pragma unroll
        for (int i = 0; i < 4; ++i)
#pragma unroll
            for (int j = 0; j < 2; ++j)
#pragma unroll
                for (int ks = 0; ks < 2; ++ks)
                    acc[4 + i][j] = __builtin_amdgcn_mfma_f32_16x16x32_bf16(
                        aF1[i][ks], bF0[j][ks], acc[4 + i][j], 0, 0, 0);
        __builtin_amdgcn_s_setprio(0);
        BARRIER();   // all waves' A-c reads complete -> A slots of c reusable

        // ---- q3: stage A(t+2) into freed c, MFMA quadrant (1,1) ----
        if (t + 2 < NT) { stage_half(t + 2, c, 0); stage_half(t + 2, c, 1); }
        __builtin_amdgcn_s_setprio(1);
#pragma unroll
        for (int i = 0; i < 4; ++i)
#pragma unroll
            for (int j = 0; j < 2; ++j)
#pragma unroll
                for (int ks = 0; ks < 2; ++ks)
                    acc[4 + i][2 + j] = __builtin_amdgcn_mfma_f32_16x16x32_bf16(
                        aF1[i][ks], bF1[j][ks], acc[4 + i][2 + j], 0, 0, 0);
        __builtin_amdgcn_s_setprio(0);
    }

    // epilogue: C/D layout col=lane&15, row=(lane>>4)*4+reg (m89/m91-verified)
#pragma unroll
    for (int m = 0; m < 8; ++m) {
        const int grow0 = rowBase + wr * 128 + m * 16 + l16 * 4;
#pragma unroll
        for (int n = 0; n < 4; ++n) {
            const int gcol = colBase + wc * 64 + n * 16 + l15;
            const float bv = bias[gcol];
#pragma unroll
            for (int r4 = 0; r4 < 4; ++r4)
                C[(size_t)(grow0 + r4) * N_DIM + gcol] = acc[m][n][r4] + bv;
        }
    }
}

extern "C" void kernel_launch(void* const* d_in, const int* in_sizes, int n_in,
                              void* d_out, int out_size, void* d_ws, size_t ws_size,
                              hipStream_t stream) {
    const float* x       = (const float*)d_in[0];
    const int*   stored  = (const int*)d_in[1];
    const int*   sign    = (const int*)d_in[2];
    const float* log_min = (const float*)d_in[3];
    const float* log_max = (const float*)d_in[4];
    const float* bias    = (const float*)d_in[5];
    float* out = (float*)d_out;

    unsigned short* Ab = (unsigned short*)d_ws;                         // 32 MB
    unsigned short* Wb = (unsigned short*)((char*)d_ws +
                          (size_t)M_DIM * K_DIM * sizeof(unsigned short)); // +128 MB

    cast_x_kernel<<<2048, 256, 0, stream>>>(x, Ab, (M_DIM * K_DIM) / 8);
    dequant_kernel<<<4096, 256, 0, stream>>>(stored, sign, log_min, log_max, Wb,
                                             (N_DIM * K_DIM) / 8);

    hipFuncSetAttribute((const void*)gemm_kernel,
                        hipFuncAttributeMaxDynamicSharedMemorySize, 131072);
    gemm_kernel<<<dim3((M_DIM / BM) * (N_DIM / BN)), dim3(512), 131072, stream>>>(
        Ab, Wb, bias, out);
}

// Round 13
// 608.172 us; speedup vs baseline: 1.0277x; 1.0160x over previous
//
#include <hip/hip_runtime.h>
#include <stdint.h>

#define M_DIM 4096   // BATCH*SEQ
#define N_DIM 16384  // OUT_FEATURES
#define K_DIM 4096   // IN_FEATURES
#define BM 256
#define BN 256
#define BK 64
#define NT (K_DIM / BK)   // 64 K-tiles

typedef __attribute__((ext_vector_type(8))) __bf16 bf16x8;
typedef __attribute__((ext_vector_type(4))) float f32x4;

// fp32 -> bf16 bits, round-to-nearest-even
__device__ __forceinline__ unsigned short f2bf(float f) {
    uint32_t u = __builtin_bit_cast(uint32_t, f);
    uint32_t r = (u + 0x7FFFu + ((u >> 16) & 1u)) >> 16;
    return (unsigned short)r;
}

union Pack8 { unsigned short h[8]; uint4 v; };

__device__ __forceinline__ void async_copy16(const void* g, void* l) {
    __builtin_amdgcn_global_load_lds((__attribute__((address_space(1))) void*)(g),
                                     (__attribute__((address_space(3))) void*)(l),
                                     16, 0, 0);
}

#define BARRIER() do { asm volatile("" ::: "memory"); \
                       __builtin_amdgcn_s_barrier();  \
                       asm volatile("" ::: "memory"); } while (0)

// ---------------- phase 0: cast x fp32 -> bf16 ----------------
__global__ __launch_bounds__(256) void cast_x_kernel(const float* __restrict__ x,
                                                     unsigned short* __restrict__ xb,
                                                     int n8) {
    for (int i = blockIdx.x * blockDim.x + threadIdx.x; i < n8;
         i += gridDim.x * blockDim.x) {
        const float4* p = (const float4*)(x + (size_t)i * 8);
        float4 v0 = p[0], v1 = p[1];
        Pack8 o;
        o.h[0] = f2bf(v0.x); o.h[1] = f2bf(v0.y);
        o.h[2] = f2bf(v0.z); o.h[3] = f2bf(v0.w);
        o.h[4] = f2bf(v1.x); o.h[5] = f2bf(v1.y);
        o.h[6] = f2bf(v1.z); o.h[7] = f2bf(v1.w);
        *(uint4*)(xb + (size_t)i * 8) = o.v;
    }
}

// ---------------- phase 1: dequant weights -> bf16 ----------------
__global__ __launch_bounds__(256) void dequant_kernel(const int* __restrict__ stored,
                                                      const int* __restrict__ sign,
                                                      const float* __restrict__ log_min,
                                                      const float* __restrict__ log_max,
                                                      unsigned short* __restrict__ wb,
                                                      int n8) {
    const float lmin = log_min[0];
    const float lrange = log_max[0] - lmin;
    for (int i = blockIdx.x * blockDim.x + threadIdx.x; i < n8;
         i += gridDim.x * blockDim.x) {
        const int4* ps = (const int4*)(stored + (size_t)i * 8);
        const int4* pg = (const int4*)(sign + (size_t)i * 8);
        int4 s0 = ps[0], s1 = ps[1];
        int4 g0 = pg[0], g1 = pg[1];
        int sv[8] = {s0.x, s0.y, s0.z, s0.w, s1.x, s1.y, s1.z, s1.w};
        int gv[8] = {g0.x, g0.y, g0.z, g0.w, g1.x, g1.y, g1.z, g1.w};
        Pack8 o;
#pragma unroll
        for (int j = 0; j < 8; ++j) {
            float nrm = (255.0f - (float)sv[j]) * (1.0f / 254.0f);
            float w = __expf(lmin + nrm * lrange);
            o.h[j] = f2bf(gv[j] ? w : -w);
        }
        *(uint4*)(wb + (size_t)i * 8) = o.v;
    }
}

// ---------------- phase 2: 256x256 bf16 GEMM, 2-barrier/K-tile, reg-pipelined ----------------
// R5/R12 configuration — empirical best (480 us GEMM, MfmaUtil 52.4%, 0 conflicts).
// Only change vs R12: C-epilogue uses NON-TEMPORAL stores (C is write-once,
// never re-read; nt keeps W panels resident in L2/L3 -> lower FETCH_SIZE).
// A: [M][K] bf16, W: [N][K] bf16, C: [M][N] fp32
// LDS (128 KiB): dbuf c: A half h at c*65536 + h*16384 (128 rows x 128 B, swizzled);
// B half h at c*65536 + 32768 + h*16384. Swizzle involution: byte ^= ((row&7)<<4);
// global_load_lds dest linear, global SOURCE pre-inverse-swizzled (rule #21).
//
// Per K-tile t (c = t&1), quadrants q=(mq,nq) of the per-wave 128x64 C-tile:
//   top:  vmcnt(4) [A(t),B(t) landed; A(t+1) still in flight]; BARRIER
//   q0:   read aF0(8) + bF0(4) + prefetch bF1(4); stage B.h0(t+1)->c^1; MFMA aF0xbF0
//   q1:   prefetch aF1(8); stage B.h1(t+1)->c^1;                        MFMA aF0xbF1
//   q2:   (read-free)                                                   MFMA aF1xbF0
//   BARRIER  [all waves' A-c reads complete -> A slots of c reusable]
//   q3:   stage A.h0+h1(t+2)->c;                                        MFMA aF1xbF1
// Cross-wave hazards: B(t+1)->c^1 safe via tile-top barrier (t-1's B reads done);
// A(t+2)->c safe via end-q2 barrier. All fragment waits: per-wave dataflow (compiler
// emits counted lgkmcnt). vmcnt ledger at top of t: [B(t) 4, A(t+1) 4] -> vmcnt(4).
__global__ __launch_bounds__(512, 2) void gemm_kernel(const unsigned short* __restrict__ A,
                                                      const unsigned short* __restrict__ W,
                                                      const float* __restrict__ bias,
                                                      float* __restrict__ C) {
    extern __shared__ char lds[];
    const int tid  = threadIdx.x;
    const int wave = tid >> 6;
    const int lane = tid & 63;
    const int l15  = lane & 15;
    const int l16  = lane >> 4;
    const int wr   = wave >> 2;   // 0..1 -> 128-row band (A half wr)
    const int wc   = wave & 3;    // 0..3 -> 64-col band (B half wc>>1, rows (wc&1)*64)

    // T1: XCD swizzle. nwg=1024 (%8==0); each XCD: 2 M-rows x all N -> A panel L2-hot.
    const int bid = blockIdx.x;
    const int wg  = ((bid & 7) << 7) | (bid >> 3);
    const int rowBase = (wg >> 6) * BM;
    const int colBase = (wg & 63) * BN;

    f32x4 acc[8][4] = {};

    // stage one half-tile u (0=A.h0,1=A.h1,2=B.h0,3=B.h1) of tile t into dbuf d
    auto stage_half = [&](int t, int d, int u) {
        const int kb = t * BK;
        const unsigned short* g = (u < 2) ? A : W;
        const int rb = ((u < 2) ? rowBase : colBase) + (u & 1) * 128;
        char* hb = lds + d * 65536 + ((u < 2) ? 0 : 32768) + (u & 1) * 16384;
#pragma unroll
        for (int sub = 0; sub < 2; ++sub) {
            const int Ld   = (sub * 512 + tid) * 16;              // linear dest byte
            const int r    = Ld >> 7;                             // row (128 B/row)
            const int colb = (Ld & 127) ^ ((r & 7) << 4);         // inverse-swz source
            async_copy16(g + (size_t)(rb + r) * K_DIM + kb + (colb >> 1),
                         hb + (sub * 512 + wave * 64) * 16);      // wave-uniform dest
        }
    };

    // prologue: tile 0 (all 4 halves) + tile 1's A halves
    stage_half(0, 0, 0); stage_half(0, 0, 1);
    stage_half(0, 0, 2); stage_half(0, 0, 3);
    stage_half(1, 1, 0); stage_half(1, 1, 1);

    for (int t = 0; t < NT; ++t) {
        const int c = t & 1;
        if (t + 1 < NT) asm volatile("s_waitcnt vmcnt(4)" ::: "memory");
        else            asm volatile("s_waitcnt vmcnt(0)" ::: "memory");
        BARRIER();

        const char* bA  = lds + c * 65536 + wr * 16384;
        const char* bB  = lds + c * 65536 + 32768 + (wc >> 1) * 16384;
        const int   brB = (wc & 1) * 64;

        bf16x8 aF0[4][2], aF1[4][2], bF0[2][2], bF1[2][2];

        // ---- q0: reads + B-prefetch + stage, then MFMA quadrant (0,0) ----
#pragma unroll
        for (int i = 0; i < 4; ++i)
#pragma unroll
            for (int ks = 0; ks < 2; ++ks) {
                const int r    = i * 16 + l15;                     // mq=0 rows 0..63
                const int colb = (ks * 64 + l16 * 16) ^ ((r & 7) << 4);
                aF0[i][ks] = *(const bf16x8*)(bA + (r << 7) + colb);
            }
#pragma unroll
        for (int j = 0; j < 2; ++j)
#pragma unroll
            for (int ks = 0; ks < 2; ++ks) {
                const int r    = brB + j * 16 + l15;               // nq=0 rows
                const int colb = (ks * 64 + l16 * 16) ^ ((r & 7) << 4);
                bF0[j][ks] = *(const bf16x8*)(bB + (r << 7) + colb);
            }
#pragma unroll
        for (int j = 0; j < 2; ++j)
#pragma unroll
            for (int ks = 0; ks < 2; ++ks) {
                const int r    = brB + 32 + j * 16 + l15;          // nq=1 rows (prefetch)
                const int colb = (ks * 64 + l16 * 16) ^ ((r & 7) << 4);
                bF1[j][ks] = *(const bf16x8*)(bB + (r << 7) + colb);
            }
        if (t + 1 < NT) stage_half(t + 1, c ^ 1, 2);               // B.h0(t+1)
        __builtin_amdgcn_s_setprio(1);
#pragma unroll
        for (int i = 0; i < 4; ++i)
#pragma unroll
            for (int j = 0; j < 2; ++j)
#pragma unroll
                for (int ks = 0; ks < 2; ++ks)
                    acc[i][j] = __builtin_amdgcn_mfma_f32_16x16x32_bf16(
                        aF0[i][ks], bF0[j][ks], acc[i][j], 0, 0, 0);
        __builtin_amdgcn_s_setprio(0);

        // ---- q1: A-prefetch + stage, MFMA quadrant (0,1) ----
#pragma unroll
        for (int i = 0; i < 4; ++i)
#pragma unroll
            for (int ks = 0; ks < 2; ++ks) {
                const int r    = 64 + i * 16 + l15;                // mq=1 rows 64..127
                const int colb = (ks * 64 + l16 * 16) ^ ((r & 7) << 4);
                aF1[i][ks] = *(const bf16x8*)(bA + (r << 7) + colb);
            }
        if (t + 1 < NT) stage_half(t + 1, c ^ 1, 3);               // B.h1(t+1)
        __builtin_amdgcn_s_setprio(1);
#pragma unroll
        for (int i = 0; i < 4; ++i)
#pragma unroll
            for (int j = 0; j < 2; ++j)
#pragma unroll
                for (int ks = 0; ks < 2; ++ks)
                    acc[i][2 + j] = __builtin_amdgcn_mfma_f32_16x16x32_bf16(
                        aF0[i][ks], bF1[j][ks], acc[i][2 + j], 0, 0, 0);
        __builtin_amdgcn_s_setprio(0);

        // ---- q2: read-free, MFMA quadrant (1,0) ----
        __builtin_amdgcn_s_setprio(1);
#pragma unroll
        for (int i = 0; i < 4; ++i)
#pragma unroll
            for (int j = 0; j < 2; ++j)
#pragma unroll
                for (int ks = 0; ks < 2; ++ks)
                    acc[4 + i][j] = __builtin_amdgcn_mfma_f32_16x16x32_bf16(
                        aF1[i][ks], bF0[j][ks], acc[4 + i][j], 0, 0, 0);
        __builtin_amdgcn_s_setprio(0);
        BARRIER();   // all waves' A-c reads complete -> A slots of c reusable

        // ---- q3: stage A(t+2) into freed c, MFMA quadrant (1,1) ----
        if (t + 2 < NT) { stage_half(t + 2, c, 0); stage_half(t + 2, c, 1); }
        __builtin_amdgcn_s_setprio(1);
#pragma unroll
        for (int i = 0; i < 4; ++i)
#pragma unroll
            for (int j = 0; j < 2; ++j)
#pragma unroll
                for (int ks = 0; ks < 2; ++ks)
                    acc[4 + i][2 + j] = __builtin_amdgcn_mfma_f32_16x16x32_bf16(
                        aF1[i][ks], bF1[j][ks], acc[4 + i][2 + j], 0, 0, 0);
        __builtin_amdgcn_s_setprio(0);
    }

    // epilogue: C/D layout col=lane&15, row=(lane>>4)*4+reg (m89/m91-verified)
    // C is write-once/never-read in this kernel: non-temporal stores keep the
    // W/A panels resident in L2/L3 (FETCH_SIZE is the diagnostic counter).
#pragma unroll
    for (int m = 0; m < 8; ++m) {
        const int grow0 = rowBase + wr * 128 + m * 16 + l16 * 4;
#pragma unroll
        for (int n = 0; n < 4; ++n) {
            const int gcol = colBase + wc * 64 + n * 16 + l15;
            const float bv = bias[gcol];
#pragma unroll
            for (int r4 = 0; r4 < 4; ++r4)
                __builtin_nontemporal_store(acc[m][n][r4] + bv,
                                            &C[(size_t)(grow0 + r4) * N_DIM + gcol]);
        }
    }
}

extern "C" void kernel_launch(void* const* d_in, const int* in_sizes, int n_in,
                              void* d_out, int out_size, void* d_ws, size_t ws_size,
                              hipStream_t stream) {
    const float* x       = (const float*)d_in[0];
    const int*   stored  = (const int*)d_in[1];
    const int*   sign    = (const int*)d_in[2];
    const float* log_min = (const float*)d_in[3];
    const float* log_max = (const float*)d_in[4];
    const float* bias    = (const float*)d_in[5];
    float* out = (float*)d_out;

    unsigned short* Ab = (unsigned short*)d_ws;                         // 32 MB
    unsigned short* Wb = (unsigned short*)((char*)d_ws +
                          (size_t)M_DIM * K_DIM * sizeof(unsigned short)); // +128 MB

    cast_x_kernel<<<2048, 256, 0, stream>>>(x, Ab, (M_DIM * K_DIM) / 8);
    dequant_kernel<<<4096, 256, 0, stream>>>(stored, sign, log_min, log_max, Wb,
                                             (N_DIM * K_DIM) / 8);

    hipFuncSetAttribute((const void*)gemm_kernel,
                        hipFuncAttributeMaxDynamicSharedMemorySize, 131072);
    gemm_kernel<<<dim3((M_DIM / BM) * (N_DIM / BN)), dim3(512), 131072, stream>>>(
        Ab, Wb, bias, out);
}